// Round 15
// baseline (248.363 us; speedup 1.0000x reference)
//
#include <hip/hip_runtime.h>

#define K_DIM 4096
#define M_DIM 12288
#define NT_K 32             // K-tiles of 128 bytes
#define BM 256              // token rows per block tile
#define BN 128              // weight rows per block tile
#define GN 16               // 4096/256 token tiles
#define GM2 96              // 12288/128 weight tiles

typedef __attribute__((ext_vector_type(4))) int i32x4;
typedef __attribute__((ext_vector_type(16))) int i32x16;
typedef __attribute__((ext_vector_type(4))) unsigned int u32x4;
typedef __attribute__((ext_vector_type(4))) float f32x4;

__device__ __forceinline__ int quant1(float v, float qs) {
  float r = rintf(v * qs);  // round half-to-even, matches jnp.round
  r = fminf(127.f, fmaxf(-128.f, r));
  return (int)r;
}

// unpack one packed byte into 4 code bytes (0..3) at permuted positions
__device__ __forceinline__ unsigned int unp(unsigned int uv) {
  return ((uv >> 6) | (uv << 4) | (uv << 14) | (uv << 24)) & 0x03030303u;
}

// Fused aux kernel (identical to round-7..13 passing version).
__global__ __launch_bounds__(256) void aux_kernel(const float* __restrict__ x,
                                                  const int* __restrict__ wp,
                                                  u32x4* __restrict__ xq2,
                                                  u32x4* __restrict__ wu2,
                                                  float2* __restrict__ scales) {
  __shared__ float redf[4];
  __shared__ int redi[4];
  __shared__ u32x4 ldsT[32][9];  // padded: 8-lane groups conflict-free both phases
  const int t = threadIdx.x;

  if (blockIdx.x < 4096) {
    // ---------------- quant path: one block per token ----------------
    const int n = blockIdx.x;
    const f32x4* __restrict__ row4 = (const f32x4*)(x + (size_t)n * K_DIM);

    float am = 0.f;
#pragma unroll
    for (int p = 0; p < 4; ++p) {
      f32x4 v = row4[t + 256 * p];
      am = fmaxf(am, fmaxf(fmaxf(fabsf(v[0]), fabsf(v[1])), fmaxf(fabsf(v[2]), fabsf(v[3]))));
    }
#pragma unroll
    for (int off = 32; off; off >>= 1) am = fmaxf(am, __shfl_xor(am, off, 64));
    const int wave = t >> 6, lane = t & 63;
    if (lane == 0) redf[wave] = am;
    __syncthreads();
    am = fmaxf(fmaxf(redf[0], redf[1]), fmaxf(redf[2], redf[3]));
    const float clipped = fmaxf(am, 1e-5f);
    const float qs = 127.0f / clipped;

    // thread t produces output chunk c = t (k' = 16t..16t+15):
    // word m packs k = (t>>3)*128 + 4*(t&7) + m + 32s, s=0..3
    f32x4 v[4];
#pragma unroll
    for (int s = 0; s < 4; ++s) v[s] = row4[(t >> 3) * 32 + (t & 7) + 8 * s];
    unsigned int wds[4];
    int rsum = 0;
#pragma unroll
    for (int m = 0; m < 4; ++m) {
      const int q0 = quant1(v[0][m], qs);
      const int q1 = quant1(v[1][m], qs);
      const int q2 = quant1(v[2][m], qs);
      const int q3 = quant1(v[3][m], qs);
      rsum += q0 + q1 + q2 + q3;
      wds[m] = (unsigned int)(q0 & 255) | ((unsigned int)(q1 & 255) << 8) |
               ((unsigned int)(q2 & 255) << 16) | ((unsigned int)(q3 & 255) << 24);
    }
    xq2[(size_t)t * 4096 + n] = (u32x4){wds[0], wds[1], wds[2], wds[3]};

#pragma unroll
    for (int off = 32; off; off >>= 1) rsum += __shfl_xor(rsum, off, 64);
    if (lane == 0) redi[wave] = rsum;
    __syncthreads();
    if (t == 0)
      scales[n] = make_float2(clipped * (1.0f / 127.0f),
                              (float)(redi[0] + redi[1] + redi[2] + redi[3]));
  } else {
    // ---------------- weight unpack + transpose path ----------------
    const int bid = blockIdx.x - 4096;  // 48 m-tiles x 32 kb
    const int mt = bid >> 5, kb = bid & 31;
    const int m0 = mt * 256;
    const i32x4* __restrict__ in4 = (const i32x4*)wp;
#pragma unroll 2
    for (int it = 0; it < 8; ++it) {
      const int m = m0 + it * 32 + (t >> 3);
      const i32x4 vv = in4[(size_t)m * 256 + kb * 8 + (t & 7)];  // coalesced 128-B runs
      ldsT[t >> 3][t & 7] = (u32x4){unp((unsigned int)vv[0]), unp((unsigned int)vv[1]),
                                    unp((unsigned int)vv[2]), unp((unsigned int)vv[3])};
      __syncthreads();
      wu2[(size_t)(kb * 8 + (t >> 5)) * M_DIM + m0 + it * 32 + (t & 31)] = ldsT[t & 31][t >> 5];
      __syncthreads();
    }
  }
}

// explicit inline-asm ds_read with literal offset (prevents compiler batching)
#define DSR(dst, addr, off) \
  asm volatile("ds_read_b128 %0, %1 offset:" #off : "=v"(dst) : "v"(addr))
#define LGKM(n) asm volatile("s_waitcnt lgkmcnt(" #n ")")
#define SB __builtin_amdgcn_sched_barrier(0)

// read the 6 fragments (4 A, 2 B) of quadrant ks into slot s.
// A slot stride 4096 (256 rows), quadrant stride 8192; B slot stride 2048
// (128 rows), quadrant stride 4096. Slot convention both: chunk = 2*ks + h.
#define RD_KS0(s) { DSR(af[s][0], aA, 0);     DSR(af[s][1], aA, 512);   DSR(af[s][2], aA, 1024);  DSR(af[s][3], aA, 1536);  DSR(bf[s][0], bA, 0);     DSR(bf[s][1], bA, 512);   }
#define RD_KS1(s) { DSR(af[s][0], aA, 8192);  DSR(af[s][1], aA, 8704);  DSR(af[s][2], aA, 9216);  DSR(af[s][3], aA, 9728);  DSR(bf[s][0], bA, 4096);  DSR(bf[s][1], bA, 4608);  }
#define RD_KS2(s) { DSR(af[s][0], aA, 16384); DSR(af[s][1], aA, 16896); DSR(af[s][2], aA, 17408); DSR(af[s][3], aA, 17920); DSR(bf[s][0], bA, 8192);  DSR(bf[s][1], bA, 8704);  }
#define RD_KS3(s) { DSR(af[s][0], aA, 24576); DSR(af[s][1], aA, 25088); DSR(af[s][2], aA, 25600); DSR(af[s][3], aA, 26112); DSR(bf[s][0], bA, 12288); DSR(bf[s][1], bA, 12800); }

#define MFMA8(s)                                                                       \
  {                                                                                    \
    __builtin_amdgcn_s_setprio(1);                                                     \
    _Pragma("unroll") for (int i_ = 0; i_ < 4; ++i_)                                   \
        _Pragma("unroll") for (int j_ = 0; j_ < 2; ++j_) acc[i_][j_] =                 \
            __builtin_amdgcn_mfma_i32_32x32x32_i8(af[s][i_], bf[s][j_], acc[i_][j_],   \
                                                  0, 0, 0);                            \
    __builtin_amdgcn_s_setprio(0);                                                     \
  }

// DESYNC experiment, corrected: 256x128 block tile, 4 waves (2x2), wave-tile
// 128x64 (R8's exact fragment addressing, ~224 regs -> 2+ waves/SIMD),
// SINGLE-buffered 48 KiB LDS -> THREE independent blocks per CU, each with
// its own barrier group. Sibling blocks drift out of phase: one block's MFMA
// burst fills the CU matrix pipe while another stages/reads — the escape
// from in-order read/MFMA alternation that 9 single-block structures could
// not provide. Race fix vs R14: sched_barrier(0) after the trailing
// s_barrier pins next-tile stage loads below it (cross-wave WAR on LDS).
// k-chunk-major LDS (conflict-free, PMC-verified), XCD block swizzle.
__global__ __launch_bounds__(256, 2) void bitgemm3b(const unsigned char* __restrict__ xq2,
                                                    const unsigned char* __restrict__ wu2,
                                                    const float2* __restrict__ scales,
                                                    const float* __restrict__ wsp,
                                                    float* __restrict__ out) {
  __shared__ __align__(16) unsigned char lds[49152];  // A [8][256][16] | B [8][128][16]

  const int tid = threadIdx.x;
  const int l = tid & 63;
  const int w = tid >> 6;  // 0..3
  const int wm = w >> 1;   // A row half 0..1
  const int wn = w & 1;    // B col half 0..1

  // XCD swizzle: 1536 blocks (%8==0 -> bijective); bn cycles fastest within
  // an XCD => 16 consecutive blocks share one B-panel (L2-hot)
  const int cpx = gridDim.x >> 3;
  const int swz = (blockIdx.x & 7) * cpx + (blockIdx.x >> 3);
  const int bn = swz & (GN - 1);
  const int bm = swz >> 4;  // 0..95

  // A staging: thread t -> row t, 8 chunk-slots (slot q, +q*65536 in global)
  const unsigned char* aBase = xq2 + ((size_t)bn * 256 + tid) * 16;
  const int ldsDstA = tid * 16;
  // B staging: thread t -> slot q*2+(t>>7), row t&127 (coalesced 2-KiB runs)
  const unsigned char* bBase =
      wu2 + ((size_t)(tid >> 7) * M_DIM + (size_t)bm * 128 + (tid & 127)) * 16;
  const int ldsDstB = 32768 + (tid >> 7) * 2048 + (tid & 127) * 16;

  // fragment read bases: lane l -> k-half h = l>>5, row = l&31
  const int aFB = (l >> 5) * 4096 + (wm * 128 + (l & 31)) * 16;
  const int bFB = (l >> 5) * 2048 + (wn * 64 + (l & 31)) * 16;
  const unsigned ldsBase = (unsigned)(size_t)lds;
  const unsigned aA = ldsBase + aFB;
  const unsigned bA = ldsBase + 32768 + bFB;

  i32x16 acc[4][2];
#pragma unroll
  for (int i = 0; i < 4; ++i)
#pragma unroll
    for (int j = 0; j < 2; ++j)
#pragma unroll
      for (int r = 0; r < 16; ++r) acc[i][j][r] = 0;

  auto stage = [&](int kb) {
    const unsigned char* as_ = aBase + (size_t)kb * 524288;   // 8 chunks * 4096 rows * 16B
    const unsigned char* bs_ = bBase + (size_t)kb * 1572864;  // 8 chunks * 12288 rows * 16B
    unsigned char* ad = lds + ldsDstA;
    unsigned char* bd = lds + ldsDstB;
#pragma unroll
    for (int q = 0; q < 8; ++q)
      __builtin_amdgcn_global_load_lds(
          (const __attribute__((address_space(1))) void*)(as_ + (size_t)q * 65536),
          (__attribute__((address_space(3))) void*)(ad + q * 4096), 16, 0, 0);
#pragma unroll
    for (int q = 0; q < 4; ++q)
      __builtin_amdgcn_global_load_lds(
          (const __attribute__((address_space(1))) void*)(bs_ + (size_t)q * 393216),
          (__attribute__((address_space(3))) void*)(bd + q * 4096), 16, 0, 0);
  };

  i32x4 af[2][4], bf[2][2];

  for (int kb = 0; kb < NT_K; ++kb) {
    // ---- stage tile kb (single buffer; sibling blocks hide the drain) ----
    stage(kb);
    asm volatile("s_waitcnt vmcnt(0)" ::: "memory");
    __builtin_amdgcn_s_barrier();
    SB;

    // ---- R8-proven per-quadrant lgkm-counted pipeline ----
    RD_KS0(0);
    RD_KS1(1);
    LGKM(6); SB;                          // ks0's 6 done; ks1's in flight
    MFMA8(0);
    RD_KS2(0);
    LGKM(6); SB;                          // ks1 done; ks2 in flight
    MFMA8(1);
    RD_KS3(1);
    LGKM(6); SB;                          // ks2 done; ks3 in flight
    MFMA8(0);
    LGKM(0); SB;                          // ks3 done
    MFMA8(1);
    __builtin_amdgcn_s_barrier();         // all waves' reads done
    SB;                                   // pin next stage BELOW the barrier (R14 race fix)
  }

  // epilogue: out = (dot_codes - rowsum) * weight_scale * act_scale
  // 32x32 C/D: col = l&31, row = (r&3) + 8*(r>>2) + 4*(l>>5)
  const float wsc = wsp[0];
#pragma unroll
  for (int i = 0; i < 4; ++i) {
#pragma unroll
    for (int r = 0; r < 16; ++r) {
      const int n = bn * BM + wm * 128 + i * 32 + (r & 3) + 8 * (r >> 2) + 4 * (l >> 5);
      const float2 sc = scales[n];
      const float f = wsc * sc.x;
      float* orow = out + (size_t)n * M_DIM + bm * BN + wn * 64 + (l & 31);
#pragma unroll
      for (int j = 0; j < 2; ++j) orow[j * 32] = ((float)acc[i][j][r] - sc.y) * f;
    }
  }
}

extern "C" void kernel_launch(void* const* d_in, const int* in_sizes, int n_in,
                              void* d_out, int out_size, void* d_ws, size_t ws_size,
                              hipStream_t stream) {
  const float* x = (const float*)d_in[0];
  const int* wp = (const int*)d_in[1];
  const float* wsp = (const float*)d_in[2];
  float* out = (float*)d_out;
  const int N = in_sizes[0] / K_DIM;  // 4096 tokens

  float2* scales = (float2*)d_ws;                                  // N * 8 B
  u32x4* xq2 = (u32x4*)((char*)d_ws + 32768);                      // 16 MB, k-major
  u32x4* wu2 = (u32x4*)((char*)d_ws + 32768 + (size_t)N * K_DIM);  // 48 MB, k-major

  aux_kernel<<<4096 + 1536, 256, 0, stream>>>(x, wp, xq2, wu2, scales);
  const int grid = GN * GM2;  // 16 * 96 = 1536
  bitgemm3b<<<grid, 256, 0, stream>>>((const unsigned char*)xq2, (const unsigned char*)wu2,
                                      scales, wsp, out);
}

// Round 16
// 230.273 us; speedup vs baseline: 1.0786x; 1.0786x over previous
//
#include <hip/hip_runtime.h>

#define K_DIM 4096
#define M_DIM 12288
#define KW 1024             // packed int32 words per weight row
#define NT_K 32             // K-tiles of 128 bytes
#define BM 256
#define BN 256
#define GN 16               // 4096/256 token tiles
#define GM 48               // 12288/256 weight tiles

typedef __attribute__((ext_vector_type(4))) int i32x4;
typedef __attribute__((ext_vector_type(16))) int i32x16;
typedef __attribute__((ext_vector_type(4))) unsigned int u32x4;
typedef __attribute__((ext_vector_type(4))) float f32x4;

__device__ __forceinline__ int quant1(float v, float qs) {
  float r = rintf(v * qs);  // round half-to-even, matches jnp.round
  r = fminf(127.f, fmaxf(-128.f, r));
  return (int)r;
}

// unpack one packed byte into 4 code bytes (0..3) at permuted positions
__device__ __forceinline__ unsigned int unp(unsigned int uv) {
  return ((uv >> 6) | (uv << 4) | (uv << 14) | (uv << 24)) & 0x03030303u;
}

// Fused aux kernel (identical to round-7..13 passing version).
__global__ __launch_bounds__(256) void aux_kernel(const float* __restrict__ x,
                                                  const int* __restrict__ wp,
                                                  u32x4* __restrict__ xq2,
                                                  u32x4* __restrict__ wu2,
                                                  float2* __restrict__ scales) {
  __shared__ float redf[4];
  __shared__ int redi[4];
  __shared__ u32x4 ldsT[32][9];  // padded: 8-lane groups conflict-free both phases
  const int t = threadIdx.x;

  if (blockIdx.x < 4096) {
    // ---------------- quant path: one block per token ----------------
    const int n = blockIdx.x;
    const f32x4* __restrict__ row4 = (const f32x4*)(x + (size_t)n * K_DIM);

    float am = 0.f;
#pragma unroll
    for (int p = 0; p < 4; ++p) {
      f32x4 v = row4[t + 256 * p];
      am = fmaxf(am, fmaxf(fmaxf(fabsf(v[0]), fabsf(v[1])), fmaxf(fabsf(v[2]), fabsf(v[3]))));
    }
#pragma unroll
    for (int off = 32; off; off >>= 1) am = fmaxf(am, __shfl_xor(am, off, 64));
    const int wave = t >> 6, lane = t & 63;
    if (lane == 0) redf[wave] = am;
    __syncthreads();
    am = fmaxf(fmaxf(redf[0], redf[1]), fmaxf(redf[2], redf[3]));
    const float clipped = fmaxf(am, 1e-5f);
    const float qs = 127.0f / clipped;

    // thread t produces output chunk c = t (k' = 16t..16t+15):
    // word m packs k = (t>>3)*128 + 4*(t&7) + m + 32s, s=0..3
    f32x4 v[4];
#pragma unroll
    for (int s = 0; s < 4; ++s) v[s] = row4[(t >> 3) * 32 + (t & 7) + 8 * s];
    unsigned int wds[4];
    int rsum = 0;
#pragma unroll
    for (int m = 0; m < 4; ++m) {
      const int q0 = quant1(v[0][m], qs);
      const int q1 = quant1(v[1][m], qs);
      const int q2 = quant1(v[2][m], qs);
      const int q3 = quant1(v[3][m], qs);
      rsum += q0 + q1 + q2 + q3;
      wds[m] = (unsigned int)(q0 & 255) | ((unsigned int)(q1 & 255) << 8) |
               ((unsigned int)(q2 & 255) << 16) | ((unsigned int)(q3 & 255) << 24);
    }
    xq2[(size_t)t * 4096 + n] = (u32x4){wds[0], wds[1], wds[2], wds[3]};

#pragma unroll
    for (int off = 32; off; off >>= 1) rsum += __shfl_xor(rsum, off, 64);
    if (lane == 0) redi[wave] = rsum;
    __syncthreads();
    if (t == 0)
      scales[n] = make_float2(clipped * (1.0f / 127.0f),
                              (float)(redi[0] + redi[1] + redi[2] + redi[3]));
  } else {
    // ---------------- weight unpack + transpose path ----------------
    const int bid = blockIdx.x - 4096;  // 48 m-tiles x 32 kb
    const int mt = bid >> 5, kb = bid & 31;
    const int m0 = mt * 256;
    const i32x4* __restrict__ in4 = (const i32x4*)wp;
#pragma unroll 2
    for (int it = 0; it < 8; ++it) {
      const int m = m0 + it * 32 + (t >> 3);
      const i32x4 vv = in4[(size_t)m * 256 + kb * 8 + (t & 7)];  // coalesced 128-B runs
      ldsT[t >> 3][t & 7] = (u32x4){unp((unsigned int)vv[0]), unp((unsigned int)vv[1]),
                                    unp((unsigned int)vv[2]), unp((unsigned int)vv[3])};
      __syncthreads();
      wu2[(size_t)(kb * 8 + (t >> 5)) * M_DIM + m0 + it * 32 + (t & 31)] = ldsT[t & 31][t >> 5];
      __syncthreads();
    }
  }
}

// explicit inline-asm ds_read with literal offset (prevents compiler batching)
#define DSR(dst, addr, off) \
  asm volatile("ds_read_b128 %0, %1 offset:" #off : "=v"(dst) : "v"(addr))
#define LGKM(n) asm volatile("s_waitcnt lgkmcnt(" #n ")")

// read the 6 fragments (4 A, 2 B) of quadrant p (literal offsets = p*8192)
#define RD_Q0 { DSR(af[0], aA, 0);     DSR(af[1], aA, 512);   DSR(af[2], aA, 1024);  DSR(af[3], aA, 1536);  DSR(bf[0], bA, 0);     DSR(bf[1], bA, 512);   }
#define RD_Q1 { DSR(af[0], aA, 8192);  DSR(af[1], aA, 8704);  DSR(af[2], aA, 9216);  DSR(af[3], aA, 9728);  DSR(bf[0], bA, 8192);  DSR(bf[1], bA, 8704);  }
#define RD_Q2 { DSR(af[0], aA, 16384); DSR(af[1], aA, 16896); DSR(af[2], aA, 17408); DSR(af[3], aA, 17920); DSR(bf[0], bA, 16384); DSR(bf[1], bA, 16896); }
#define RD_Q3 { DSR(af[0], aA, 24576); DSR(af[1], aA, 25088); DSR(af[2], aA, 25600); DSR(af[3], aA, 26112); DSR(bf[0], bA, 24576); DSR(bf[1], bA, 25088); }

#define MFMA8                                                                          \
  {                                                                                    \
    __builtin_amdgcn_s_setprio(1);                                                     \
    _Pragma("unroll") for (int i_ = 0; i_ < 4; ++i_)                                   \
        _Pragma("unroll") for (int j_ = 0; j_ < 2; ++j_) acc[i_][j_] =                 \
            __builtin_amdgcn_mfma_i32_32x32x32_i8(af[i_], bf[j_], acc[i_][j_],         \
                                                  0, 0, 0);                            \
    __builtin_amdgcn_s_setprio(0);                                                     \
  }

// phase 0: VALIDATED entry — stage next pair, counted vmcnt (tile kb's 8
// landed, next tile's 2 in flight), barrier, THEN read buf[cur].
#define PHASE0(STG, WAITC)               \
  {                                      \
    STG;                                 \
    WAITC;                               \
    __builtin_amdgcn_s_barrier();        \
    __builtin_amdgcn_sched_barrier(0);   \
    RD_Q0;                               \
    LGKM(0);                             \
    __builtin_amdgcn_sched_barrier(0);   \
    MFMA8;                               \
    __builtin_amdgcn_s_barrier();        \
  }

// phases 1-3: m201 read-hiding form — reads (of the already-validated buf)
// + stage pair BEFORE barrier (barrier wait hides read latency), lgkm(0)
// after, MFMA cluster, trailing barrier.
#define PHASE(RD, STG)                   \
  {                                      \
    RD;                                  \
    STG;                                 \
    __builtin_amdgcn_s_barrier();        \
    LGKM(0);                             \
    __builtin_amdgcn_sched_barrier(0);   \
    MFMA8;                               \
    __builtin_amdgcn_s_barrier();        \
  }

// 256x256 tile, BK=128 B, 8 waves (2 row-halves x 4 col-quarters), wave-tile
// 128x64, mfma_i32_32x32x32_i8, k-chunk-major LDS (conflict-free, PMC-
// verified). 8-barrier/tile m201 schedule with race-free phase 0; stage
// split 2-loads/phase; single counted vmcnt(2) per tile (never 0 mid-loop).
// XCD block swizzle. BEST MEASURED: 229.6 / 231.3 us total (rounds 11/13).
__global__ __launch_bounds__(512, 2) void bitgemm32(const unsigned char* __restrict__ xq2,
                                                    const unsigned char* __restrict__ wu2,
                                                    const float2* __restrict__ scales,
                                                    const float* __restrict__ wsp,
                                                    float* __restrict__ out) {
  __shared__ __align__(16) unsigned char lds[131072];  // A [2][32K] | B [2][32K]

  const int tid = threadIdx.x;
  const int l = tid & 63;
  const int w = tid >> 6;  // 0..7
  const int wm = w >> 2;   // row half 0..1
  const int wn = w & 3;    // col quarter 0..3

  // XCD swizzle: 768 blocks (%8==0 -> bijective), bm-major within each XCD
  const int cpx = gridDim.x >> 3;
  const int swz = (blockIdx.x & 7) * cpx + (blockIdx.x >> 3);
  const int bn = swz & (GN - 1);
  const int bm = swz >> 4;

  // staging: thread t writes LDS chunk-slot (q*2 + (t>>8), row t&255); source
  // chunk c = kb*8 + q*2 + (t>>8) at the same row -> contiguous 4-KiB runs.
  const unsigned char* aBase =
      xq2 + ((size_t)(tid >> 8) * 4096 + (size_t)bn * 256 + (tid & 255)) * 16;
  const unsigned char* bBase =
      wu2 + ((size_t)(tid >> 8) * 12288 + (size_t)bm * 256 + (tid & 255)) * 16;
  const int ldsDst = tid * 16;

  // fragment read base offsets: lane l -> k-half h = l>>5, row/col = l&31
  const int aFB = (l >> 5) * 4096 + (wm * 128 + (l & 31)) * 16;
  const int bFB = (l >> 5) * 4096 + (wn * 64 + (l & 31)) * 16;
  const unsigned ldsBase = (unsigned)(size_t)lds;

  i32x16 acc[4][2];
#pragma unroll
  for (int i = 0; i < 4; ++i)
#pragma unroll
    for (int j = 0; j < 2; ++j)
#pragma unroll
      for (int r = 0; r < 16; ++r) acc[i][j][r] = 0;

  // stage quarter q of tile kb into buffer buf (2 gloads: 1 A + 1 B)
  auto stageQ = [&](int buf, int kb, int q) {
    __builtin_amdgcn_global_load_lds(
        (const __attribute__((address_space(1))) void*)(aBase + (size_t)kb * 524288 +
                                                        (size_t)q * 131072),
        (__attribute__((address_space(3))) void*)(lds + buf * 32768 + ldsDst + q * 8192), 16, 0,
        0);
    __builtin_amdgcn_global_load_lds(
        (const __attribute__((address_space(1))) void*)(bBase + (size_t)kb * 1572864 +
                                                        (size_t)q * 393216),
        (__attribute__((address_space(3))) void*)(lds + 65536 + buf * 32768 + ldsDst + q * 8192),
        16, 0, 0);
  };

  i32x4 af[4], bf[2];

  // prologue: stage all of tile 0
#pragma unroll
  for (int q = 0; q < 4; ++q) stageQ(0, 0, q);

  for (int kb = 0; kb < NT_K; ++kb) {
    const int cur = kb & 1;
    const int nbuf = cur ^ 1;
    const bool pf = (kb + 1 < NT_K);
    const unsigned aA = ldsBase + cur * 32768 + aFB;
    const unsigned bA = ldsBase + 65536 + cur * 32768 + bFB;

    if (pf) {
      PHASE0(stageQ(nbuf, kb + 1, 0), asm volatile("s_waitcnt vmcnt(2)" ::: "memory"));
      PHASE(RD_Q1, stageQ(nbuf, kb + 1, 1));
      PHASE(RD_Q2, stageQ(nbuf, kb + 1, 2));
      PHASE(RD_Q3, stageQ(nbuf, kb + 1, 3));
    } else {
      PHASE0(, asm volatile("s_waitcnt vmcnt(0)" ::: "memory"));
      PHASE(RD_Q1, );
      PHASE(RD_Q2, );
      PHASE(RD_Q3, );
    }
  }

  // epilogue: out = (dot_codes - rowsum) * weight_scale * act_scale
  // 32x32 C/D: col = l&31, row = (r&3) + 8*(r>>2) + 4*(l>>5)
  const float wsc = wsp[0];
#pragma unroll
  for (int i = 0; i < 4; ++i) {
#pragma unroll
    for (int r = 0; r < 16; ++r) {
      const int n = bn * BM + wm * 128 + i * 32 + (r & 3) + 8 * (r >> 2) + 4 * (l >> 5);
      const float2 sc = scales[n];
      const float f = wsc * sc.x;
      float* orow = out + (size_t)n * M_DIM + bm * BN + wn * 64 + (l & 31);
#pragma unroll
      for (int j = 0; j < 2; ++j) orow[j * 32] = ((float)acc[i][j][r] - sc.y) * f;
    }
  }
}

extern "C" void kernel_launch(void* const* d_in, const int* in_sizes, int n_in,
                              void* d_out, int out_size, void* d_ws, size_t ws_size,
                              hipStream_t stream) {
  const float* x = (const float*)d_in[0];
  const int* wp = (const int*)d_in[1];
  const float* wsp = (const float*)d_in[2];
  float* out = (float*)d_out;
  const int N = in_sizes[0] / K_DIM;  // 4096 tokens

  float2* scales = (float2*)d_ws;                                  // N * 8 B
  u32x4* xq2 = (u32x4*)((char*)d_ws + 32768);                      // 16 MB, k-major
  u32x4* wu2 = (u32x4*)((char*)d_ws + 32768 + (size_t)N * K_DIM);  // 48 MB, k-major

  aux_kernel<<<4096 + 1536, 256, 0, stream>>>(x, wp, xq2, wu2, scales);
  const int grid = (N / BM) * GM;  // 768
  bitgemm32<<<grid, 512, 0, stream>>>((const unsigned char*)xq2, (const unsigned char*)wu2,
                                      scales, wsp, out);
}